// Round 6
// baseline (429.163 us; speedup 1.0000x reference)
//
#include <hip/hip_runtime.h>
#include <hip/hip_fp16.h>

#define NN   200000
#define EE   6400000
#define INC  128
#define HIDC 16
#define OUTC 2

#define TN     256                 // nodes per dst tile
#define TSHIFT 8
#define TMASK  (TN - 1)
#define NT     782                 // ceil(NN / TN)
#define CHUNK  8192                // edges per place block (58.5 KB LDS, 2 blocks/CU)
#define NBE    782                 // ceil(EE / CHUNK)
#define SCAP   9216                // fixed per-tile segment capacity (mean 8184, +11 sigma)

// ---------------- init per-tile allocation cursors (no hist/scan needed) ----
__global__ __launch_bounds__(1024) void k_init(int* __restrict__ gcur) {
    int t = threadIdx.x;
    if (t < NT) gcur[t] = t * SCAP;
}

// ---------------- place edges: block-local counting sort + burst write ------
// record = (src << 8) | (dst & 255); brec has fixed SCAP-sized tile segments.
__global__ __launch_bounds__(256) void k_place(const int* __restrict__ src,
                                               const int* __restrict__ dst,
                                               int* __restrict__ gcur,
                                               int* __restrict__ brec) {
    __shared__ int h[NT];                      // per-tile counts
    __shared__ int lbase[NT];                  // local excl scan; then insert cursor
    __shared__ int gofs[NT];                   // global_base - local_base
    __shared__ int stmp[256];                  // block scan temp
    __shared__ int lrec[CHUNK];                // 32 KB sorted records
    __shared__ unsigned short ltid[CHUNK];     // 16 KB tile id per record

    int tid = threadIdx.x;
    int base = blockIdx.x * CHUNK;
    int nrec = EE - base; if (nrec > CHUNK) nrec = CHUNK;
    bool full = (base + CHUNK <= EE);

    // ---- phase 1: histogram ----
    for (int t = tid; t < NT; t += 256) h[t] = 0;
    __syncthreads();
    if (full) {
        for (int i = tid; i < CHUNK; i += 1024) {
            int d0 = dst[base + i];
            int d1 = dst[base + i + 256];
            int d2 = dst[base + i + 512];
            int d3 = dst[base + i + 768];
            atomicAdd(&h[d0 >> TSHIFT], 1);
            atomicAdd(&h[d1 >> TSHIFT], 1);
            atomicAdd(&h[d2 >> TSHIFT], 1);
            atomicAdd(&h[d3 >> TSHIFT], 1);
        }
    } else {
        for (int i = tid; i < nrec; i += 256)
            atomicAdd(&h[dst[base + i] >> TSHIFT], 1);
    }
    __syncthreads();

    // ---- phase 2: exclusive scan of h -> lbase (4 tiles per thread) ----
    int t0 = tid * 4;
    int c0 = (t0 + 0 < NT) ? h[t0 + 0] : 0;
    int c1 = (t0 + 1 < NT) ? h[t0 + 1] : 0;
    int c2 = (t0 + 2 < NT) ? h[t0 + 2] : 0;
    int c3 = (t0 + 3 < NT) ? h[t0 + 3] : 0;
    int s = c0 + c1 + c2 + c3;
    stmp[tid] = s;
    __syncthreads();
    for (int o = 1; o < 256; o <<= 1) {
        int u = (tid >= o) ? stmp[tid - o] : 0;
        __syncthreads();
        stmp[tid] += u;
        __syncthreads();
    }
    int run = stmp[tid] - s;                   // exclusive prefix of this thread's span
    if (t0 + 0 < NT) { lbase[t0 + 0] = run; run += c0; }
    if (t0 + 1 < NT) { lbase[t0 + 1] = run; run += c1; }
    if (t0 + 2 < NT) { lbase[t0 + 2] = run; run += c2; }
    if (t0 + 3 < NT) { lbase[t0 + 3] = run; run += c3; }
    __syncthreads();

    // ---- phase 3: reserve global ranges (one atomic per non-empty tile) ----
    for (int t = tid; t < NT; t += 256) {
        int c = h[t];
        int gb = c ? atomicAdd(&gcur[t], c) : 0;
        gofs[t] = gb - lbase[t];
    }
    __syncthreads();

    // ---- phase 4: scatter into LDS, sorted by tile (lbase becomes cursor) ----
    if (full) {
        for (int i = tid; i < CHUNK; i += 1024) {
            int e = base + i;
            int d0 = dst[e], d1 = dst[e + 256], d2 = dst[e + 512], d3 = dst[e + 768];
            int s0 = src[e], s1 = src[e + 256], s2 = src[e + 512], s3 = src[e + 768];
            int t0_ = d0 >> TSHIFT, t1_ = d1 >> TSHIFT;
            int t2_ = d2 >> TSHIFT, t3_ = d3 >> TSHIFT;
            int p0 = atomicAdd(&lbase[t0_], 1);
            int p1 = atomicAdd(&lbase[t1_], 1);
            int p2 = atomicAdd(&lbase[t2_], 1);
            int p3 = atomicAdd(&lbase[t3_], 1);
            lrec[p0] = (s0 << 8) | (d0 & TMASK); ltid[p0] = (unsigned short)t0_;
            lrec[p1] = (s1 << 8) | (d1 & TMASK); ltid[p1] = (unsigned short)t1_;
            lrec[p2] = (s2 << 8) | (d2 & TMASK); ltid[p2] = (unsigned short)t2_;
            lrec[p3] = (s3 << 8) | (d3 & TMASK); ltid[p3] = (unsigned short)t3_;
        }
    } else {
        for (int i = tid; i < nrec; i += 256) {
            int e = base + i;
            int d = dst[e], ss = src[e];
            int tt = d >> TSHIFT;
            int p = atomicAdd(&lbase[tt], 1);
            lrec[p] = (ss << 8) | (d & TMASK); ltid[p] = (unsigned short)tt;
        }
    }
    __syncthreads();

    // ---- phase 5: burst writeout (consecutive i in a tile -> consecutive g) --
    for (int i = tid; i < nrec; i += 256) {
        int r = lrec[i];
        int tt = ltid[i];
        brec[gofs[tt] + i] = r;
    }
}

// ---------------- per-tile counting sort -> node-sorted CSR (in place) ------
// tile t's records live in [t*SCAP, gcur[t]); nstart points into padded brec.
__global__ __launch_bounds__(256) void k_sortt(int* __restrict__ brec,
                                               const int* __restrict__ gcur,
                                               int* __restrict__ nstart,
                                               int* __restrict__ ndeg) {
    __shared__ int rec[SCAP];                  // 36 KB
    __shared__ int hist[TN];
    __shared__ int scn[TN];
    __shared__ int cur[TN];
    int t = blockIdx.x;
    int s0 = t * SCAP;
    int cnt = gcur[t] - s0;
    if (cnt > SCAP) cnt = SCAP;                // deterministic input: never hit
    if (threadIdx.x < TN) hist[threadIdx.x] = 0;
    __syncthreads();
    for (int i = threadIdx.x; i < cnt; i += 256) {
        int r = brec[s0 + i];
        rec[i] = r;
        atomicAdd(&hist[r & TMASK], 1);
    }
    __syncthreads();
    if (threadIdx.x < TN) scn[threadIdx.x] = hist[threadIdx.x];
    __syncthreads();
    for (int o = 1; o < TN; o <<= 1) {
        int u = (threadIdx.x >= o && threadIdx.x < TN) ? scn[threadIdx.x - o] : 0;
        __syncthreads();
        if (threadIdx.x < TN) scn[threadIdx.x] += u;
        __syncthreads();
    }
    if (threadIdx.x < TN) {
        int ex = scn[threadIdx.x] - hist[threadIdx.x];
        cur[threadIdx.x] = ex;
        int node = t * TN + threadIdx.x;
        if (node < NN) {
            nstart[node] = s0 + ex;
            ndeg[node] = hist[threadIdx.x];
        }
    }
    __syncthreads();
    for (int i = threadIdx.x; i < cnt; i += 256) {
        int r = rec[i];
        int pos = atomicAdd(&cur[r & TMASK], 1);
        brec[s0 + pos] = r >> 8;               // store src id, node-sorted
    }
}

// ---------------- g1 = dinv * (x @ W1), stored fp16 -------------------------
__global__ __launch_bounds__(256) void k_xw(const float* __restrict__ x,
                                            const float* __restrict__ W1,
                                            const int* __restrict__ ndeg,
                                            __half2* __restrict__ g1) {
    __shared__ float Ws[INC * HIDC];           // 8 KB
    for (int j = threadIdx.x; j < INC * HIDC; j += 256) Ws[j] = W1[j];
    __syncthreads();
    int n = blockIdx.x * 256 + threadIdx.x;
    if (n >= NN) return;
    const float4* xr = (const float4*)(x + (size_t)n * INC);
    float acc[HIDC];
#pragma unroll
    for (int c = 0; c < HIDC; ++c) acc[c] = 0.f;
    for (int k4 = 0; k4 < INC / 4; ++k4) {
        float4 xv = xr[k4];
        const float* w0 = &Ws[(k4 * 4) * HIDC];
        float xs[4] = {xv.x, xv.y, xv.z, xv.w};
#pragma unroll
        for (int j = 0; j < 4; ++j) {
#pragma unroll
            for (int c = 0; c < HIDC; ++c) acc[c] += xs[j] * w0[j * HIDC + c];
        }
    }
    float dn = rsqrtf((float)(ndeg[n] + 1));   // +1 self-loop
    union { __half2 h[8]; float4 f[2]; } u;
#pragma unroll
    for (int q = 0; q < 8; ++q)
        u.h[q] = __floats2half2_rn(dn * acc[2 * q], dn * acc[2 * q + 1]);
    float4* gp = (float4*)(g1 + (size_t)n * 8);
    gp[0] = u.f[0];
    gp[1] = u.f[1];
}

// ---------------- layer-1 gather + fused MLP (fp16 rows, no atomics) --------
// 2 lanes per node; lane owns 8 channels (one 16 B half-row). 4 rows (64 B)
// in flight per lane for latency hiding; width-2 shuffle reduce at the end.
__global__ __launch_bounds__(256) void k_agg1w(const int* __restrict__ csr,
                                               const int* __restrict__ nstart,
                                               const int* __restrict__ ndeg,
                                               const float4* __restrict__ g1,
                                               const float* __restrict__ b1,
                                               const float* __restrict__ W2,
                                               float* __restrict__ g2) {
    int lane = threadIdx.x & 1;
    int n = (blockIdx.x * 256 + threadIdx.x) >> 1;
    if (n >= NN) return;
    int rs = nstart[n];
    int deg = ndeg[n];
    int re = rs + deg;
    float dn = rsqrtf((float)(deg + 1));
    float acc[8];
    {   // self-loop
        float4 sv = g1[(size_t)n * 2 + lane];
        const __half2* sh = (const __half2*)&sv;
#pragma unroll
        for (int q = 0; q < 4; ++q) {
            float2 f = __half22float2(sh[q]);
            acc[2 * q] = f.x; acc[2 * q + 1] = f.y;
        }
    }
    int i = rs;
    for (; i + 4 <= re; i += 4) {              // 4x16B row-halves in flight
        int s0 = csr[i], s1 = csr[i + 1], s2 = csr[i + 2], s3 = csr[i + 3];
        float4 v0 = g1[(size_t)s0 * 2 + lane];
        float4 v1 = g1[(size_t)s1 * 2 + lane];
        float4 v2 = g1[(size_t)s2 * 2 + lane];
        float4 v3 = g1[(size_t)s3 * 2 + lane];
        const __half2* h0 = (const __half2*)&v0;
        const __half2* h1 = (const __half2*)&v1;
        const __half2* h2 = (const __half2*)&v2;
        const __half2* h3 = (const __half2*)&v3;
#pragma unroll
        for (int q = 0; q < 4; ++q) {
            float2 f0 = __half22float2(h0[q]);
            float2 f1 = __half22float2(h1[q]);
            float2 f2 = __half22float2(h2[q]);
            float2 f3 = __half22float2(h3[q]);
            acc[2 * q]     += (f0.x + f1.x) + (f2.x + f3.x);
            acc[2 * q + 1] += (f0.y + f1.y) + (f2.y + f3.y);
        }
    }
    for (; i < re; ++i) {
        float4 v = g1[(size_t)csr[i] * 2 + lane];
        const __half2* h = (const __half2*)&v;
#pragma unroll
        for (int q = 0; q < 4; ++q) {
            float2 f = __half22float2(h[q]);
            acc[2 * q] += f.x; acc[2 * q + 1] += f.y;
        }
    }
    int c0 = lane * 8;
    float p0 = 0.f, p1 = 0.f;
#pragma unroll
    for (int j = 0; j < 8; ++j) {
        float h = fmaxf(fmaf(dn, acc[j], b1[c0 + j]), 0.f);
        p0 = fmaf(h, W2[(c0 + j) * OUTC + 0], p0);
        p1 = fmaf(h, W2[(c0 + j) * OUTC + 1], p1);
    }
    p0 += __shfl_xor(p0, 1, 2);
    p1 += __shfl_xor(p1, 1, 2);
    if (lane == 0) {
        float2 v; v.x = dn * p0; v.y = dn * p1;
        ((float2*)g2)[n] = v;
    }
}

// ---------------- layer-2 gather + final epilogue (no atomics) --------------
__global__ __launch_bounds__(256) void k_agg2n(const int* __restrict__ csr,
                                               const int* __restrict__ nstart,
                                               const int* __restrict__ ndeg,
                                               const float* __restrict__ g2,
                                               const float* __restrict__ b2,
                                               float* __restrict__ out) {
    int lane = threadIdx.x & 7;
    int n = (blockIdx.x * 256 + threadIdx.x) >> 3;
    if (n >= NN) return;
    int rs = nstart[n];
    int deg = ndeg[n];
    int re = rs + deg;
    float dn = rsqrtf((float)(deg + 1));
    float ax = 0.f, ay = 0.f;
    for (int i = rs + lane; i < re; i += 8) {
        float2 v = ((const float2*)g2)[csr[i]];
        ax += v.x; ay += v.y;
    }
#pragma unroll
    for (int o = 4; o; o >>= 1) {
        ax += __shfl_xor(ax, o, 8);
        ay += __shfl_xor(ay, o, 8);
    }
    if (lane == 0) {
        float2 g = ((const float2*)g2)[n];
        float2 o2;
        o2.x = fmaf(dn, ax + g.x, b2[0]);
        o2.y = fmaf(dn, ay + g.y, b2[1]);
        ((float2*)out)[n] = o2;
    }
}

// ======================= fallback (atomic scatter) kernels ==================

__global__ void k_deg_f(const int* __restrict__ dst, int* __restrict__ deg) {
    int i = blockIdx.x * blockDim.x + threadIdx.x;
    if (i < EE) atomicAdd(&deg[dst[i]], 1);
}
__global__ void k_dinv_f(const int* __restrict__ deg, float* __restrict__ dinv) {
    int n = blockIdx.x * blockDim.x + threadIdx.x;
    if (n < NN) dinv[n] = rsqrtf((float)(deg[n] + 1));
}
__global__ void k_xw_f(const float* __restrict__ x, const float* __restrict__ W1,
                       const float* __restrict__ dinv, float* __restrict__ g1) {
    __shared__ float Ws[INC * HIDC];
    for (int j = threadIdx.x; j < INC * HIDC; j += 256) Ws[j] = W1[j];
    __syncthreads();
    int n = blockIdx.x * 256 + threadIdx.x;
    if (n >= NN) return;
    const float4* xr = (const float4*)(x + (size_t)n * INC);
    float acc[HIDC];
#pragma unroll
    for (int c = 0; c < HIDC; ++c) acc[c] = 0.f;
    for (int k4 = 0; k4 < INC / 4; ++k4) {
        float4 xv = xr[k4];
        const float* w0 = &Ws[(k4 * 4) * HIDC];
        float xs[4] = {xv.x, xv.y, xv.z, xv.w};
#pragma unroll
        for (int j = 0; j < 4; ++j)
#pragma unroll
            for (int c = 0; c < HIDC; ++c) acc[c] += xs[j] * w0[j * HIDC + c];
    }
    float dn = dinv[n];
#pragma unroll
    for (int c = 0; c < HIDC; ++c) g1[(size_t)n * HIDC + c] = dn * acc[c];
}
__global__ void k_scatter1_f(const int* __restrict__ src, const int* __restrict__ dst,
                             const float* __restrict__ g1, float* __restrict__ acc1) {
    int i = blockIdx.x * blockDim.x + threadIdx.x;
    if (i >= EE * 4) return;
    int e = i >> 2, q = i & 3;
    float4 v = ((const float4*)g1)[src[e] * 4 + q];
    float* p = acc1 + (size_t)dst[e] * HIDC + q * 4;
    unsafeAtomicAdd(p + 0, v.x); unsafeAtomicAdd(p + 1, v.y);
    unsafeAtomicAdd(p + 2, v.z); unsafeAtomicAdd(p + 3, v.w);
}
__global__ void k_l2_f(const float* __restrict__ g1, const float* __restrict__ acc1,
                       const float* __restrict__ dinv, const float* __restrict__ b1,
                       const float* __restrict__ W2, float* __restrict__ g2) {
    int n = blockIdx.x * blockDim.x + threadIdx.x;
    if (n >= NN) return;
    float dn = dinv[n];
    float h[HIDC];
#pragma unroll
    for (int c = 0; c < HIDC; ++c)
        h[c] = fmaxf(dn * (acc1[(size_t)n * HIDC + c] + g1[(size_t)n * HIDC + c]) + b1[c], 0.f);
    float o0 = 0.f, o1 = 0.f;
#pragma unroll
    for (int c = 0; c < HIDC; ++c) { o0 += h[c] * W2[c * 2]; o1 += h[c] * W2[c * 2 + 1]; }
    g2[(size_t)n * 2] = dn * o0; g2[(size_t)n * 2 + 1] = dn * o1;
}
__global__ void k_scatter2_f(const int* __restrict__ src, const int* __restrict__ dst,
                             const float* __restrict__ g2, float* __restrict__ acc2) {
    int e = blockIdx.x * blockDim.x + threadIdx.x;
    if (e >= EE) return;
    float2 v = ((const float2*)g2)[src[e]];
    unsafeAtomicAdd(&acc2[(size_t)dst[e] * 2], v.x);
    unsafeAtomicAdd(&acc2[(size_t)dst[e] * 2 + 1], v.y);
}
__global__ void k_final_f(const float* __restrict__ g2, const float* __restrict__ acc2,
                          const float* __restrict__ dinv, const float* __restrict__ b2,
                          float* __restrict__ out) {
    int n = blockIdx.x * blockDim.x + threadIdx.x;
    if (n >= NN) return;
    float dn = dinv[n];
    float2 a = ((const float2*)acc2)[n];
    float2 g = ((const float2*)g2)[n];
    float2 o;
    o.x = dn * (a.x + g.x) + b2[0];
    o.y = dn * (a.y + g.y) + b2[1];
    ((float2*)out)[n] = o;
}

// ======================= launch =============================================

extern "C" void kernel_launch(void* const* d_in, const int* in_sizes, int n_in,
                              void* d_out, int out_size, void* d_ws, size_t ws_size,
                              hipStream_t stream) {
    const float* x  = (const float*)d_in[0];
    const int*   ei = (const int*)d_in[1];     // [2, E] flat: src then dst
    const float* W1 = (const float*)d_in[2];
    const float* b1 = (const float*)d_in[3];
    const float* W2 = (const float*)d_in[4];
    const float* b2 = (const float*)d_in[5];
    float* out = (float*)d_out;

    const int* src = ei;
    const int* dst = ei + EE;
    const int B = 256;

    // CSR-path workspace (4 B elements), total ~38.4 MB:
    //   gcur        [0, NT)
    //   brec/csr    [NT, NT + NT*SCAP)   fixed-capacity tile segments
    //   nstart      [.., + N+1)
    //   ndeg        [.., + N)
    //   g1 (fp16)   [.., + 8N)   16 halves/row
    //   g2 (fp32)   [.., + 2N)
    size_t need = ((size_t)NT + (size_t)NT * SCAP + (size_t)(NN + 1) + (size_t)NN +
                   (size_t)8 * NN + (size_t)2 * NN) * 4;
    if (ws_size >= need) {
        int* ws          = (int*)d_ws;
        int* gcur        = ws;
        int* brec        = ws + NT;                   // becomes node-sorted CSR
        int* nstart      = brec + (size_t)NT * SCAP;
        int* ndeg        = nstart + NN + 1;
        __half2* g1      = (__half2*)(ndeg + NN);
        float* g2        = (float*)((int*)(ndeg + NN) + (size_t)8 * NN);

        k_init  <<<1, 1024, 0, stream>>>(gcur);
        k_place <<<NBE, 256, 0, stream>>>(src, dst, gcur, brec);
        k_sortt <<<NT, 256, 0, stream>>>(brec, gcur, nstart, ndeg);
        k_xw    <<<(NN + 255) / 256, 256, 0, stream>>>(x, W1, ndeg, g1);
        k_agg1w <<<(NN * 2 + 255) / 256, 256, 0, stream>>>(brec, nstart, ndeg,
                                                           (const float4*)g1, b1, W2, g2);
        k_agg2n <<<(NN * 8 + 255) / 256, 256, 0, stream>>>(brec, nstart, ndeg, g2, b2, out);
        return;
    }

    // -------- fallback: atomic-scatter path (needs 38N floats ~ 30.4 MB) ----
    char* wsb = (char*)d_ws;
    int*   deg  = (int*)wsb;
    float* acc1 = (float*)(wsb + (size_t)NN * 4);
    float* acc2 = (float*)(wsb + (size_t)17 * NN * 4);
    float* dinv = (float*)(wsb + (size_t)19 * NN * 4);
    float* g1   = (float*)(wsb + (size_t)20 * NN * 4);
    float* g2   = (float*)(wsb + (size_t)36 * NN * 4);

    hipMemsetAsync(d_ws, 0, (size_t)19 * NN * 4, stream);

    int gN = (NN + B - 1) / B, gE = (EE + B - 1) / B, gE4 = (EE * 4 + B - 1) / B;
    k_deg_f     <<<gE, B, 0, stream>>>(dst, deg);
    k_dinv_f    <<<gN, B, 0, stream>>>(deg, dinv);
    k_xw_f      <<<gN, B, 0, stream>>>(x, W1, dinv, g1);
    k_scatter1_f<<<gE4, B, 0, stream>>>(src, dst, g1, acc1);
    k_l2_f      <<<gN, B, 0, stream>>>(g1, acc1, dinv, b1, W2, g2);
    k_scatter2_f<<<gE, B, 0, stream>>>(src, dst, g2, acc2);
    k_final_f   <<<gN, B, 0, stream>>>(g2, acc2, dinv, b2, out);
}

// Round 7
// 407.598 us; speedup vs baseline: 1.0529x; 1.0529x over previous
//
#include <hip/hip_runtime.h>
#include <hip/hip_fp16.h>

#define NN   200000
#define EE   6400000
#define INC  128
#define HIDC 16
#define OUTC 2

#define TN     256                 // nodes per dst tile
#define TSHIFT 8
#define TMASK  (TN - 1)
#define NT     782                 // ceil(NN / TN)
#define CHUNK  8192                // edges per place block (58.5 KB LDS, 2 blocks/CU)
#define NBE    782                 // ceil(EE / CHUNK)
#define SCAP   9216                // fixed per-tile segment capacity (mean 8184, +11 sigma)
#define QDIV   50000u              // src-quarter width (NN/4): 1.6 MB of g1 per quarter

// ---------------- init per-tile allocation cursors (no hist/scan needed) ----
__global__ __launch_bounds__(1024) void k_init(int* __restrict__ gcur) {
    int t = threadIdx.x;
    if (t < NT) gcur[t] = t * SCAP;
}

// ---------------- place edges: block-local counting sort + burst write ------
// record = (src << 8) | (dst & 255); brec has fixed SCAP-sized tile segments.
__global__ __launch_bounds__(256) void k_place(const int* __restrict__ src,
                                               const int* __restrict__ dst,
                                               int* __restrict__ gcur,
                                               int* __restrict__ brec) {
    __shared__ int h[NT];                      // per-tile counts
    __shared__ int lbase[NT];                  // local excl scan; then insert cursor
    __shared__ int gofs[NT];                   // global_base - local_base
    __shared__ int stmp[256];                  // block scan temp
    __shared__ int lrec[CHUNK];                // 32 KB sorted records
    __shared__ unsigned short ltid[CHUNK];     // 16 KB tile id per record

    int tid = threadIdx.x;
    int base = blockIdx.x * CHUNK;
    int nrec = EE - base; if (nrec > CHUNK) nrec = CHUNK;
    bool full = (base + CHUNK <= EE);

    // ---- phase 1: histogram ----
    for (int t = tid; t < NT; t += 256) h[t] = 0;
    __syncthreads();
    if (full) {
        for (int i = tid; i < CHUNK; i += 1024) {
            int d0 = dst[base + i];
            int d1 = dst[base + i + 256];
            int d2 = dst[base + i + 512];
            int d3 = dst[base + i + 768];
            atomicAdd(&h[d0 >> TSHIFT], 1);
            atomicAdd(&h[d1 >> TSHIFT], 1);
            atomicAdd(&h[d2 >> TSHIFT], 1);
            atomicAdd(&h[d3 >> TSHIFT], 1);
        }
    } else {
        for (int i = tid; i < nrec; i += 256)
            atomicAdd(&h[dst[base + i] >> TSHIFT], 1);
    }
    __syncthreads();

    // ---- phase 2: exclusive scan of h -> lbase (4 tiles per thread) ----
    int t0 = tid * 4;
    int c0 = (t0 + 0 < NT) ? h[t0 + 0] : 0;
    int c1 = (t0 + 1 < NT) ? h[t0 + 1] : 0;
    int c2 = (t0 + 2 < NT) ? h[t0 + 2] : 0;
    int c3 = (t0 + 3 < NT) ? h[t0 + 3] : 0;
    int s = c0 + c1 + c2 + c3;
    stmp[tid] = s;
    __syncthreads();
    for (int o = 1; o < 256; o <<= 1) {
        int u = (tid >= o) ? stmp[tid - o] : 0;
        __syncthreads();
        stmp[tid] += u;
        __syncthreads();
    }
    int run = stmp[tid] - s;                   // exclusive prefix of this thread's span
    if (t0 + 0 < NT) { lbase[t0 + 0] = run; run += c0; }
    if (t0 + 1 < NT) { lbase[t0 + 1] = run; run += c1; }
    if (t0 + 2 < NT) { lbase[t0 + 2] = run; run += c2; }
    if (t0 + 3 < NT) { lbase[t0 + 3] = run; run += c3; }
    __syncthreads();

    // ---- phase 3: reserve global ranges (one atomic per non-empty tile) ----
    for (int t = tid; t < NT; t += 256) {
        int c = h[t];
        int gb = c ? atomicAdd(&gcur[t], c) : 0;
        gofs[t] = gb - lbase[t];
    }
    __syncthreads();

    // ---- phase 4: scatter into LDS, sorted by tile (lbase becomes cursor) ----
    if (full) {
        for (int i = tid; i < CHUNK; i += 1024) {
            int e = base + i;
            int d0 = dst[e], d1 = dst[e + 256], d2 = dst[e + 512], d3 = dst[e + 768];
            int s0 = src[e], s1 = src[e + 256], s2 = src[e + 512], s3 = src[e + 768];
            int t0_ = d0 >> TSHIFT, t1_ = d1 >> TSHIFT;
            int t2_ = d2 >> TSHIFT, t3_ = d3 >> TSHIFT;
            int p0 = atomicAdd(&lbase[t0_], 1);
            int p1 = atomicAdd(&lbase[t1_], 1);
            int p2 = atomicAdd(&lbase[t2_], 1);
            int p3 = atomicAdd(&lbase[t3_], 1);
            lrec[p0] = (s0 << 8) | (d0 & TMASK); ltid[p0] = (unsigned short)t0_;
            lrec[p1] = (s1 << 8) | (d1 & TMASK); ltid[p1] = (unsigned short)t1_;
            lrec[p2] = (s2 << 8) | (d2 & TMASK); ltid[p2] = (unsigned short)t2_;
            lrec[p3] = (s3 << 8) | (d3 & TMASK); ltid[p3] = (unsigned short)t3_;
        }
    } else {
        for (int i = tid; i < nrec; i += 256) {
            int e = base + i;
            int d = dst[e], ss = src[e];
            int tt = d >> TSHIFT;
            int p = atomicAdd(&lbase[tt], 1);
            lrec[p] = (ss << 8) | (d & TMASK); ltid[p] = (unsigned short)tt;
        }
    }
    __syncthreads();

    // ---- phase 5: burst writeout (consecutive i in a tile -> consecutive g) --
    for (int i = tid; i < nrec; i += 256) {
        int r = lrec[i];
        int tt = ltid[i];
        brec[gofs[tt] + i] = r;
    }
}

// ---------------- per-tile counting sort -> node+quarter-sorted CSR ---------
// key = (local_dst << 2) | src_quarter. Each node's src list ends up grouped
// by 1.6 MB g1 quarter -> the layer-1 gather sweeps the table region by
// region instead of uniformly at random (L2 residency per phase).
// tile t's records live in [t*SCAP, gcur[t]); nstart points into padded brec.
__global__ __launch_bounds__(256) void k_sortt(int* __restrict__ brec,
                                               const int* __restrict__ gcur,
                                               int* __restrict__ nstart,
                                               int* __restrict__ ndeg) {
    __shared__ int rec[SCAP];                  // 36 KB
    __shared__ int h[1024];                    // 4 KB  per-(node,quarter) counts
    __shared__ int cur[1024];                  // 4 KB  insert cursors
    __shared__ int stmp[256];                  // 1 KB
    int t = blockIdx.x;
    int s0 = t * SCAP;
    int cnt = gcur[t] - s0;
    if (cnt > SCAP) cnt = SCAP;                // deterministic input: never hit
    int tid = threadIdx.x;
    for (int k = tid; k < 1024; k += 256) h[k] = 0;
    __syncthreads();
    for (int i = tid; i < cnt; i += 256) {
        int r = brec[s0 + i];
        rec[i] = r;
        unsigned q = (unsigned)(r >> 8) / QDIV;            // src quarter 0..3
        atomicAdd(&h[((unsigned)(r & TMASK) << 2) | q], 1);
    }
    __syncthreads();
    // scan of 1024 buckets: thread tid owns node tid's 4 quarter-buckets
    int k0 = tid * 4;
    int c0 = h[k0], c1 = h[k0 + 1], c2 = h[k0 + 2], c3 = h[k0 + 3];
    int s = c0 + c1 + c2 + c3;
    stmp[tid] = s;
    __syncthreads();
    for (int o = 1; o < 256; o <<= 1) {
        int u = (tid >= o) ? stmp[tid - o] : 0;
        __syncthreads();
        stmp[tid] += u;
        __syncthreads();
    }
    int run = stmp[tid] - s;                   // exclusive prefix of this node
    int node = t * TN + tid;
    if (node < NN) {
        nstart[node] = s0 + run;
        ndeg[node] = s;
    }
    cur[k0] = run;     run += c0;
    cur[k0 + 1] = run; run += c1;
    cur[k0 + 2] = run; run += c2;
    cur[k0 + 3] = run;
    __syncthreads();
    for (int i = tid; i < cnt; i += 256) {
        int r = rec[i];
        unsigned q = (unsigned)(r >> 8) / QDIV;
        int pos = atomicAdd(&cur[((unsigned)(r & TMASK) << 2) | q], 1);
        brec[s0 + pos] = r >> 8;               // store src id, (node,quarter)-sorted
    }
}

// ---------------- g1 = dinv * (x @ W1), stored fp16 -------------------------
__global__ __launch_bounds__(256) void k_xw(const float* __restrict__ x,
                                            const float* __restrict__ W1,
                                            const int* __restrict__ ndeg,
                                            __half2* __restrict__ g1) {
    __shared__ float Ws[INC * HIDC];           // 8 KB
    for (int j = threadIdx.x; j < INC * HIDC; j += 256) Ws[j] = W1[j];
    __syncthreads();
    int n = blockIdx.x * 256 + threadIdx.x;
    if (n >= NN) return;
    const float4* xr = (const float4*)(x + (size_t)n * INC);
    float acc[HIDC];
#pragma unroll
    for (int c = 0; c < HIDC; ++c) acc[c] = 0.f;
    for (int k4 = 0; k4 < INC / 4; ++k4) {
        float4 xv = xr[k4];
        const float* w0 = &Ws[(k4 * 4) * HIDC];
        float xs[4] = {xv.x, xv.y, xv.z, xv.w};
#pragma unroll
        for (int j = 0; j < 4; ++j) {
#pragma unroll
            for (int c = 0; c < HIDC; ++c) acc[c] += xs[j] * w0[j * HIDC + c];
        }
    }
    float dn = rsqrtf((float)(ndeg[n] + 1));   // +1 self-loop
    union { __half2 h[8]; float4 f[2]; } u;
#pragma unroll
    for (int q = 0; q < 8; ++q)
        u.h[q] = __floats2half2_rn(dn * acc[2 * q], dn * acc[2 * q + 1]);
    float4* gp = (float4*)(g1 + (size_t)n * 8);
    gp[0] = u.f[0];
    gp[1] = u.f[1];
}

// ---------------- layer-1 gather + fused MLP (fp16 rows, no atomics) --------
// 8 lanes per node, lane owns channels {2c, 2c+1}; 32 B coalesced row/edge.
__global__ __launch_bounds__(256) void k_agg1n(const int* __restrict__ csr,
                                               const int* __restrict__ nstart,
                                               const int* __restrict__ ndeg,
                                               const __half2* __restrict__ g1,
                                               const float* __restrict__ b1,
                                               const float* __restrict__ W2,
                                               float* __restrict__ g2) {
    int lane = threadIdx.x & 7;
    int n = (blockIdx.x * 256 + threadIdx.x) >> 3;
    if (n >= NN) return;
    int rs = nstart[n];
    int deg = ndeg[n];
    int re = rs + deg;
    float dn = rsqrtf((float)(deg + 1));
    float2 s = __half22float2(g1[(size_t)n * 8 + lane]);   // self-loop
    float ax = s.x, ay = s.y;
    int i = rs;
    for (; i + 4 <= re; i += 4) {              // 4 row-loads in flight
        int s0 = csr[i], s1 = csr[i + 1], s2 = csr[i + 2], s3 = csr[i + 3];
        float2 f0 = __half22float2(g1[(size_t)s0 * 8 + lane]);
        float2 f1 = __half22float2(g1[(size_t)s1 * 8 + lane]);
        float2 f2 = __half22float2(g1[(size_t)s2 * 8 + lane]);
        float2 f3 = __half22float2(g1[(size_t)s3 * 8 + lane]);
        ax += f0.x + f1.x + f2.x + f3.x;
        ay += f0.y + f1.y + f2.y + f3.y;
    }
    for (; i < re; ++i) {
        float2 f = __half22float2(g1[(size_t)csr[i] * 8 + lane]);
        ax += f.x; ay += f.y;
    }
    float h0 = fmaxf(fmaf(dn, ax, b1[2 * lane]), 0.f);
    float h1 = fmaxf(fmaf(dn, ay, b1[2 * lane + 1]), 0.f);
    float p0 = h0 * W2[(2 * lane) * OUTC + 0] + h1 * W2[(2 * lane + 1) * OUTC + 0];
    float p1 = h0 * W2[(2 * lane) * OUTC + 1] + h1 * W2[(2 * lane + 1) * OUTC + 1];
#pragma unroll
    for (int o = 4; o; o >>= 1) {
        p0 += __shfl_xor(p0, o, 8);
        p1 += __shfl_xor(p1, o, 8);
    }
    if (lane == 0) {
        float2 v; v.x = dn * p0; v.y = dn * p1;
        ((float2*)g2)[n] = v;
    }
}

// ---------------- layer-2 gather + final epilogue (no atomics) --------------
__global__ __launch_bounds__(256) void k_agg2n(const int* __restrict__ csr,
                                               const int* __restrict__ nstart,
                                               const int* __restrict__ ndeg,
                                               const float* __restrict__ g2,
                                               const float* __restrict__ b2,
                                               float* __restrict__ out) {
    int lane = threadIdx.x & 7;
    int n = (blockIdx.x * 256 + threadIdx.x) >> 3;
    if (n >= NN) return;
    int rs = nstart[n];
    int deg = ndeg[n];
    int re = rs + deg;
    float dn = rsqrtf((float)(deg + 1));
    float ax = 0.f, ay = 0.f;
    for (int i = rs + lane; i < re; i += 8) {
        float2 v = ((const float2*)g2)[csr[i]];
        ax += v.x; ay += v.y;
    }
#pragma unroll
    for (int o = 4; o; o >>= 1) {
        ax += __shfl_xor(ax, o, 8);
        ay += __shfl_xor(ay, o, 8);
    }
    if (lane == 0) {
        float2 g = ((const float2*)g2)[n];
        float2 o2;
        o2.x = fmaf(dn, ax + g.x, b2[0]);
        o2.y = fmaf(dn, ay + g.y, b2[1]);
        ((float2*)out)[n] = o2;
    }
}

// ======================= fallback (atomic scatter) kernels ==================

__global__ void k_deg_f(const int* __restrict__ dst, int* __restrict__ deg) {
    int i = blockIdx.x * blockDim.x + threadIdx.x;
    if (i < EE) atomicAdd(&deg[dst[i]], 1);
}
__global__ void k_dinv_f(const int* __restrict__ deg, float* __restrict__ dinv) {
    int n = blockIdx.x * blockDim.x + threadIdx.x;
    if (n < NN) dinv[n] = rsqrtf((float)(deg[n] + 1));
}
__global__ void k_xw_f(const float* __restrict__ x, const float* __restrict__ W1,
                       const float* __restrict__ dinv, float* __restrict__ g1) {
    __shared__ float Ws[INC * HIDC];
    for (int j = threadIdx.x; j < INC * HIDC; j += 256) Ws[j] = W1[j];
    __syncthreads();
    int n = blockIdx.x * 256 + threadIdx.x;
    if (n >= NN) return;
    const float4* xr = (const float4*)(x + (size_t)n * INC);
    float acc[HIDC];
#pragma unroll
    for (int c = 0; c < HIDC; ++c) acc[c] = 0.f;
    for (int k4 = 0; k4 < INC / 4; ++k4) {
        float4 xv = xr[k4];
        const float* w0 = &Ws[(k4 * 4) * HIDC];
        float xs[4] = {xv.x, xv.y, xv.z, xv.w};
#pragma unroll
        for (int j = 0; j < 4; ++j)
#pragma unroll
            for (int c = 0; c < HIDC; ++c) acc[c] += xs[j] * w0[j * HIDC + c];
    }
    float dn = dinv[n];
#pragma unroll
    for (int c = 0; c < HIDC; ++c) g1[(size_t)n * HIDC + c] = dn * acc[c];
}
__global__ void k_scatter1_f(const int* __restrict__ src, const int* __restrict__ dst,
                             const float* __restrict__ g1, float* __restrict__ acc1) {
    int i = blockIdx.x * blockDim.x + threadIdx.x;
    if (i >= EE * 4) return;
    int e = i >> 2, q = i & 3;
    float4 v = ((const float4*)g1)[src[e] * 4 + q];
    float* p = acc1 + (size_t)dst[e] * HIDC + q * 4;
    unsafeAtomicAdd(p + 0, v.x); unsafeAtomicAdd(p + 1, v.y);
    unsafeAtomicAdd(p + 2, v.z); unsafeAtomicAdd(p + 3, v.w);
}
__global__ void k_l2_f(const float* __restrict__ g1, const float* __restrict__ acc1,
                       const float* __restrict__ dinv, const float* __restrict__ b1,
                       const float* __restrict__ W2, float* __restrict__ g2) {
    int n = blockIdx.x * blockDim.x + threadIdx.x;
    if (n >= NN) return;
    float dn = dinv[n];
    float h[HIDC];
#pragma unroll
    for (int c = 0; c < HIDC; ++c)
        h[c] = fmaxf(dn * (acc1[(size_t)n * HIDC + c] + g1[(size_t)n * HIDC + c]) + b1[c], 0.f);
    float o0 = 0.f, o1 = 0.f;
#pragma unroll
    for (int c = 0; c < HIDC; ++c) { o0 += h[c] * W2[c * 2]; o1 += h[c] * W2[c * 2 + 1]; }
    g2[(size_t)n * 2] = dn * o0; g2[(size_t)n * 2 + 1] = dn * o1;
}
__global__ void k_scatter2_f(const int* __restrict__ src, const int* __restrict__ dst,
                             const float* __restrict__ g2, float* __restrict__ acc2) {
    int e = blockIdx.x * blockDim.x + threadIdx.x;
    if (e >= EE) return;
    float2 v = ((const float2*)g2)[src[e]];
    unsafeAtomicAdd(&acc2[(size_t)dst[e] * 2], v.x);
    unsafeAtomicAdd(&acc2[(size_t)dst[e] * 2 + 1], v.y);
}
__global__ void k_final_f(const float* __restrict__ g2, const float* __restrict__ acc2,
                          const float* __restrict__ dinv, const float* __restrict__ b2,
                          float* __restrict__ out) {
    int n = blockIdx.x * blockDim.x + threadIdx.x;
    if (n >= NN) return;
    float dn = dinv[n];
    float2 a = ((const float2*)acc2)[n];
    float2 g = ((const float2*)g2)[n];
    float2 o;
    o.x = dn * (a.x + g.x) + b2[0];
    o.y = dn * (a.y + g.y) + b2[1];
    ((float2*)out)[n] = o;
}

// ======================= launch =============================================

extern "C" void kernel_launch(void* const* d_in, const int* in_sizes, int n_in,
                              void* d_out, int out_size, void* d_ws, size_t ws_size,
                              hipStream_t stream) {
    const float* x  = (const float*)d_in[0];
    const int*   ei = (const int*)d_in[1];     // [2, E] flat: src then dst
    const float* W1 = (const float*)d_in[2];
    const float* b1 = (const float*)d_in[3];
    const float* W2 = (const float*)d_in[4];
    const float* b2 = (const float*)d_in[5];
    float* out = (float*)d_out;

    const int* src = ei;
    const int* dst = ei + EE;
    const int B = 256;

    // CSR-path workspace (4 B elements), total ~38.4 MB:
    //   gcur        [0, NT)
    //   brec/csr    [NT, NT + NT*SCAP)   fixed-capacity tile segments
    //   nstart      [.., + N+1)
    //   ndeg        [.., + N)
    //   g1 (fp16)   [.., + 8N)   16 halves/row
    //   g2 (fp32)   [.., + 2N)
    size_t need = ((size_t)NT + (size_t)NT * SCAP + (size_t)(NN + 1) + (size_t)NN +
                   (size_t)8 * NN + (size_t)2 * NN) * 4;
    if (ws_size >= need) {
        int* ws          = (int*)d_ws;
        int* gcur        = ws;
        int* brec        = ws + NT;                   // becomes node-sorted CSR
        int* nstart      = brec + (size_t)NT * SCAP;
        int* ndeg        = nstart + NN + 1;
        __half2* g1      = (__half2*)(ndeg + NN);
        float* g2        = (float*)((int*)(ndeg + NN) + (size_t)8 * NN);

        k_init  <<<1, 1024, 0, stream>>>(gcur);
        k_place <<<NBE, 256, 0, stream>>>(src, dst, gcur, brec);
        k_sortt <<<NT, 256, 0, stream>>>(brec, gcur, nstart, ndeg);
        k_xw    <<<(NN + 255) / 256, 256, 0, stream>>>(x, W1, ndeg, g1);
        k_agg1n <<<(NN * 8 + 255) / 256, 256, 0, stream>>>(brec, nstart, ndeg, g1, b1, W2, g2);
        k_agg2n <<<(NN * 8 + 255) / 256, 256, 0, stream>>>(brec, nstart, ndeg, g2, b2, out);
        return;
    }

    // -------- fallback: atomic-scatter path (needs 38N floats ~ 30.4 MB) ----
    char* wsb = (char*)d_ws;
    int*   deg  = (int*)wsb;
    float* acc1 = (float*)(wsb + (size_t)NN * 4);
    float* acc2 = (float*)(wsb + (size_t)17 * NN * 4);
    float* dinv = (float*)(wsb + (size_t)19 * NN * 4);
    float* g1   = (float*)(wsb + (size_t)20 * NN * 4);
    float* g2   = (float*)(wsb + (size_t)36 * NN * 4);

    hipMemsetAsync(d_ws, 0, (size_t)19 * NN * 4, stream);

    int gN = (NN + B - 1) / B, gE = (EE + B - 1) / B, gE4 = (EE * 4 + B - 1) / B;
    k_deg_f     <<<gE, B, 0, stream>>>(dst, deg);
    k_dinv_f    <<<gN, B, 0, stream>>>(deg, dinv);
    k_xw_f      <<<gN, B, 0, stream>>>(x, W1, dinv, g1);
    k_scatter1_f<<<gE4, B, 0, stream>>>(src, dst, g1, acc1);
    k_l2_f      <<<gN, B, 0, stream>>>(g1, acc1, dinv, b1, W2, g2);
    k_scatter2_f<<<gE, B, 0, stream>>>(src, dst, g2, acc2);
    k_final_f   <<<gN, B, 0, stream>>>(g2, acc2, dinv, b2, out);
}

// Round 8
// 407.075 us; speedup vs baseline: 1.0543x; 1.0013x over previous
//
#include <hip/hip_runtime.h>
#include <hip/hip_fp16.h>

#define NN   200000
#define EE   6400000
#define INC  128
#define HIDC 16
#define OUTC 2

#define TN     256                 // nodes per dst tile
#define TSHIFT 8
#define TMASK  (TN - 1)
#define NT     782                 // ceil(NN / TN)
#define CHUNK  8192                // edges per place block (58.5 KB LDS, 2 blocks/CU)
#define NBE    782                 // ceil(EE / CHUNK)
#define SCAP   9216                // fixed per-tile segment capacity (mean 8184, +11 sigma)
#define QSH    15                  // src-region shift: regions of 32768 nodes (1.05 MB g1)
#define NQ     8                   // region buckets per node (src>>15 in 0..6)

// ---------------- init per-tile allocation cursors (no hist/scan needed) ----
__global__ __launch_bounds__(1024) void k_init(int* __restrict__ gcur) {
    int t = threadIdx.x;
    if (t < NT) gcur[t] = t * SCAP;
}

// ---------------- place edges: block-local counting sort + burst write ------
// record = (src << 8) | (dst & 255); brec has fixed SCAP-sized tile segments.
__global__ __launch_bounds__(256) void k_place(const int* __restrict__ src,
                                               const int* __restrict__ dst,
                                               int* __restrict__ gcur,
                                               int* __restrict__ brec) {
    __shared__ int h[NT];                      // per-tile counts
    __shared__ int lbase[NT];                  // local excl scan; then insert cursor
    __shared__ int gofs[NT];                   // global_base - local_base
    __shared__ int stmp[256];                  // block scan temp
    __shared__ int lrec[CHUNK];                // 32 KB sorted records
    __shared__ unsigned short ltid[CHUNK];     // 16 KB tile id per record

    int tid = threadIdx.x;
    int base = blockIdx.x * CHUNK;
    int nrec = EE - base; if (nrec > CHUNK) nrec = CHUNK;
    bool full = (base + CHUNK <= EE);

    // ---- phase 1: histogram ----
    for (int t = tid; t < NT; t += 256) h[t] = 0;
    __syncthreads();
    if (full) {
        for (int i = tid; i < CHUNK; i += 1024) {
            int d0 = dst[base + i];
            int d1 = dst[base + i + 256];
            int d2 = dst[base + i + 512];
            int d3 = dst[base + i + 768];
            atomicAdd(&h[d0 >> TSHIFT], 1);
            atomicAdd(&h[d1 >> TSHIFT], 1);
            atomicAdd(&h[d2 >> TSHIFT], 1);
            atomicAdd(&h[d3 >> TSHIFT], 1);
        }
    } else {
        for (int i = tid; i < nrec; i += 256)
            atomicAdd(&h[dst[base + i] >> TSHIFT], 1);
    }
    __syncthreads();

    // ---- phase 2: exclusive scan of h -> lbase (4 tiles per thread) ----
    int t0 = tid * 4;
    int c0 = (t0 + 0 < NT) ? h[t0 + 0] : 0;
    int c1 = (t0 + 1 < NT) ? h[t0 + 1] : 0;
    int c2 = (t0 + 2 < NT) ? h[t0 + 2] : 0;
    int c3 = (t0 + 3 < NT) ? h[t0 + 3] : 0;
    int s = c0 + c1 + c2 + c3;
    stmp[tid] = s;
    __syncthreads();
    for (int o = 1; o < 256; o <<= 1) {
        int u = (tid >= o) ? stmp[tid - o] : 0;
        __syncthreads();
        stmp[tid] += u;
        __syncthreads();
    }
    int run = stmp[tid] - s;                   // exclusive prefix of this thread's span
    if (t0 + 0 < NT) { lbase[t0 + 0] = run; run += c0; }
    if (t0 + 1 < NT) { lbase[t0 + 1] = run; run += c1; }
    if (t0 + 2 < NT) { lbase[t0 + 2] = run; run += c2; }
    if (t0 + 3 < NT) { lbase[t0 + 3] = run; run += c3; }
    __syncthreads();

    // ---- phase 3: reserve global ranges (one atomic per non-empty tile) ----
    for (int t = tid; t < NT; t += 256) {
        int c = h[t];
        int gb = c ? atomicAdd(&gcur[t], c) : 0;
        gofs[t] = gb - lbase[t];
    }
    __syncthreads();

    // ---- phase 4: scatter into LDS, sorted by tile (lbase becomes cursor) ----
    if (full) {
        for (int i = tid; i < CHUNK; i += 1024) {
            int e = base + i;
            int d0 = dst[e], d1 = dst[e + 256], d2 = dst[e + 512], d3 = dst[e + 768];
            int s0 = src[e], s1 = src[e + 256], s2 = src[e + 512], s3 = src[e + 768];
            int t0_ = d0 >> TSHIFT, t1_ = d1 >> TSHIFT;
            int t2_ = d2 >> TSHIFT, t3_ = d3 >> TSHIFT;
            int p0 = atomicAdd(&lbase[t0_], 1);
            int p1 = atomicAdd(&lbase[t1_], 1);
            int p2 = atomicAdd(&lbase[t2_], 1);
            int p3 = atomicAdd(&lbase[t3_], 1);
            lrec[p0] = (s0 << 8) | (d0 & TMASK); ltid[p0] = (unsigned short)t0_;
            lrec[p1] = (s1 << 8) | (d1 & TMASK); ltid[p1] = (unsigned short)t1_;
            lrec[p2] = (s2 << 8) | (d2 & TMASK); ltid[p2] = (unsigned short)t2_;
            lrec[p3] = (s3 << 8) | (d3 & TMASK); ltid[p3] = (unsigned short)t3_;
        }
    } else {
        for (int i = tid; i < nrec; i += 256) {
            int e = base + i;
            int d = dst[e], ss = src[e];
            int tt = d >> TSHIFT;
            int p = atomicAdd(&lbase[tt], 1);
            lrec[p] = (ss << 8) | (d & TMASK); ltid[p] = (unsigned short)tt;
        }
    }
    __syncthreads();

    // ---- phase 5: burst writeout (consecutive i in a tile -> consecutive g) --
    for (int i = tid; i < nrec; i += 256) {
        int r = lrec[i];
        int tt = ltid[i];
        brec[gofs[tt] + i] = r;
    }
}

// ---------------- per-tile counting sort -> node+region-sorted CSR ----------
// key = (local_dst << 3) | (src >> QSH). Each node's src list ends up grouped
// by 1.05 MB g1 region -> the layer-1 gather sweeps the table region by
// region instead of uniformly at random (L2 residency per phase).
// tile t's records live in [t*SCAP, gcur[t]); nstart points into padded brec.
__global__ __launch_bounds__(256) void k_sortt(int* __restrict__ brec,
                                               const int* __restrict__ gcur,
                                               int* __restrict__ nstart,
                                               int* __restrict__ ndeg) {
    __shared__ int rec[SCAP];                  // 36 KB
    __shared__ int h[TN * NQ];                 // 8 KB  per-(node,region) counts
    __shared__ int cur[TN * NQ];               // 8 KB  insert cursors
    __shared__ int stmp[256];                  // 1 KB
    int t = blockIdx.x;
    int s0 = t * SCAP;
    int cnt = gcur[t] - s0;
    if (cnt > SCAP) cnt = SCAP;                // deterministic input: never hit
    int tid = threadIdx.x;
    for (int k = tid; k < TN * NQ; k += 256) h[k] = 0;
    __syncthreads();
    for (int i = tid; i < cnt; i += 256) {
        int r = brec[s0 + i];
        rec[i] = r;
        unsigned q = (unsigned)(r >> 8) >> QSH;            // src region 0..6
        atomicAdd(&h[((unsigned)(r & TMASK) << 3) | q], 1);
    }
    __syncthreads();
    // scan of 2048 buckets: thread tid owns node tid's 8 region-buckets
    int k0 = tid * NQ;
    int s = 0;
#pragma unroll
    for (int j = 0; j < NQ; ++j) s += h[k0 + j];
    stmp[tid] = s;
    __syncthreads();
    for (int o = 1; o < 256; o <<= 1) {
        int u = (tid >= o) ? stmp[tid - o] : 0;
        __syncthreads();
        stmp[tid] += u;
        __syncthreads();
    }
    int run = stmp[tid] - s;                   // exclusive prefix of this node
    int node = t * TN + tid;
    if (node < NN) {
        nstart[node] = s0 + run;
        ndeg[node] = s;
    }
#pragma unroll
    for (int j = 0; j < NQ; ++j) {
        cur[k0 + j] = run;
        run += h[k0 + j];
    }
    __syncthreads();
    for (int i = tid; i < cnt; i += 256) {
        int r = rec[i];
        unsigned q = (unsigned)(r >> 8) >> QSH;
        int pos = atomicAdd(&cur[((unsigned)(r & TMASK) << 3) | q], 1);
        brec[s0 + pos] = r >> 8;               // store src id, (node,region)-sorted
    }
}

// ---------------- g1 = dinv * (x @ W1), stored fp16 -------------------------
__global__ __launch_bounds__(256) void k_xw(const float* __restrict__ x,
                                            const float* __restrict__ W1,
                                            const int* __restrict__ ndeg,
                                            __half2* __restrict__ g1) {
    __shared__ float Ws[INC * HIDC];           // 8 KB
    for (int j = threadIdx.x; j < INC * HIDC; j += 256) Ws[j] = W1[j];
    __syncthreads();
    int n = blockIdx.x * 256 + threadIdx.x;
    if (n >= NN) return;
    const float4* xr = (const float4*)(x + (size_t)n * INC);
    float acc[HIDC];
#pragma unroll
    for (int c = 0; c < HIDC; ++c) acc[c] = 0.f;
    for (int k4 = 0; k4 < INC / 4; ++k4) {
        float4 xv = xr[k4];
        const float* w0 = &Ws[(k4 * 4) * HIDC];
        float xs[4] = {xv.x, xv.y, xv.z, xv.w};
#pragma unroll
        for (int j = 0; j < 4; ++j) {
#pragma unroll
            for (int c = 0; c < HIDC; ++c) acc[c] += xs[j] * w0[j * HIDC + c];
        }
    }
    float dn = rsqrtf((float)(ndeg[n] + 1));   // +1 self-loop
    union { __half2 h[8]; float4 f[2]; } u;
#pragma unroll
    for (int q = 0; q < 8; ++q)
        u.h[q] = __floats2half2_rn(dn * acc[2 * q], dn * acc[2 * q + 1]);
    float4* gp = (float4*)(g1 + (size_t)n * 8);
    gp[0] = u.f[0];
    gp[1] = u.f[1];
}

// ---------------- layer-1 gather + fused MLP (fp16 rows, no atomics) --------
// 8 lanes per node, lane owns channels {2c, 2c+1}; 32 B coalesced row/edge.
__global__ __launch_bounds__(256) void k_agg1n(const int* __restrict__ csr,
                                               const int* __restrict__ nstart,
                                               const int* __restrict__ ndeg,
                                               const __half2* __restrict__ g1,
                                               const float* __restrict__ b1,
                                               const float* __restrict__ W2,
                                               float* __restrict__ g2) {
    int lane = threadIdx.x & 7;
    int n = (blockIdx.x * 256 + threadIdx.x) >> 3;
    if (n >= NN) return;
    int rs = nstart[n];
    int deg = ndeg[n];
    int re = rs + deg;
    float dn = rsqrtf((float)(deg + 1));
    float2 s = __half22float2(g1[(size_t)n * 8 + lane]);   // self-loop
    float ax = s.x, ay = s.y;
    int i = rs;
    for (; i + 4 <= re; i += 4) {              // 4 row-loads in flight
        int s0 = csr[i], s1 = csr[i + 1], s2 = csr[i + 2], s3 = csr[i + 3];
        float2 f0 = __half22float2(g1[(size_t)s0 * 8 + lane]);
        float2 f1 = __half22float2(g1[(size_t)s1 * 8 + lane]);
        float2 f2 = __half22float2(g1[(size_t)s2 * 8 + lane]);
        float2 f3 = __half22float2(g1[(size_t)s3 * 8 + lane]);
        ax += f0.x + f1.x + f2.x + f3.x;
        ay += f0.y + f1.y + f2.y + f3.y;
    }
    for (; i < re; ++i) {
        float2 f = __half22float2(g1[(size_t)csr[i] * 8 + lane]);
        ax += f.x; ay += f.y;
    }
    float h0 = fmaxf(fmaf(dn, ax, b1[2 * lane]), 0.f);
    float h1 = fmaxf(fmaf(dn, ay, b1[2 * lane + 1]), 0.f);
    float p0 = h0 * W2[(2 * lane) * OUTC + 0] + h1 * W2[(2 * lane + 1) * OUTC + 0];
    float p1 = h0 * W2[(2 * lane) * OUTC + 1] + h1 * W2[(2 * lane + 1) * OUTC + 1];
#pragma unroll
    for (int o = 4; o; o >>= 1) {
        p0 += __shfl_xor(p0, o, 8);
        p1 += __shfl_xor(p1, o, 8);
    }
    if (lane == 0) {
        float2 v; v.x = dn * p0; v.y = dn * p1;
        ((float2*)g2)[n] = v;
    }
}

// ---------------- layer-2 gather + final epilogue (no atomics) --------------
__global__ __launch_bounds__(256) void k_agg2n(const int* __restrict__ csr,
                                               const int* __restrict__ nstart,
                                               const int* __restrict__ ndeg,
                                               const float* __restrict__ g2,
                                               const float* __restrict__ b2,
                                               float* __restrict__ out) {
    int lane = threadIdx.x & 7;
    int n = (blockIdx.x * 256 + threadIdx.x) >> 3;
    if (n >= NN) return;
    int rs = nstart[n];
    int deg = ndeg[n];
    int re = rs + deg;
    float dn = rsqrtf((float)(deg + 1));
    float ax = 0.f, ay = 0.f;
    for (int i = rs + lane; i < re; i += 8) {
        float2 v = ((const float2*)g2)[csr[i]];
        ax += v.x; ay += v.y;
    }
#pragma unroll
    for (int o = 4; o; o >>= 1) {
        ax += __shfl_xor(ax, o, 8);
        ay += __shfl_xor(ay, o, 8);
    }
    if (lane == 0) {
        float2 g = ((const float2*)g2)[n];
        float2 o2;
        o2.x = fmaf(dn, ax + g.x, b2[0]);
        o2.y = fmaf(dn, ay + g.y, b2[1]);
        ((float2*)out)[n] = o2;
    }
}

// ======================= fallback (atomic scatter) kernels ==================

__global__ void k_deg_f(const int* __restrict__ dst, int* __restrict__ deg) {
    int i = blockIdx.x * blockDim.x + threadIdx.x;
    if (i < EE) atomicAdd(&deg[dst[i]], 1);
}
__global__ void k_dinv_f(const int* __restrict__ deg, float* __restrict__ dinv) {
    int n = blockIdx.x * blockDim.x + threadIdx.x;
    if (n < NN) dinv[n] = rsqrtf((float)(deg[n] + 1));
}
__global__ void k_xw_f(const float* __restrict__ x, const float* __restrict__ W1,
                       const float* __restrict__ dinv, float* __restrict__ g1) {
    __shared__ float Ws[INC * HIDC];
    for (int j = threadIdx.x; j < INC * HIDC; j += 256) Ws[j] = W1[j];
    __syncthreads();
    int n = blockIdx.x * 256 + threadIdx.x;
    if (n >= NN) return;
    const float4* xr = (const float4*)(x + (size_t)n * INC);
    float acc[HIDC];
#pragma unroll
    for (int c = 0; c < HIDC; ++c) acc[c] = 0.f;
    for (int k4 = 0; k4 < INC / 4; ++k4) {
        float4 xv = xr[k4];
        const float* w0 = &Ws[(k4 * 4) * HIDC];
        float xs[4] = {xv.x, xv.y, xv.z, xv.w};
#pragma unroll
        for (int j = 0; j < 4; ++j)
#pragma unroll
            for (int c = 0; c < HIDC; ++c) acc[c] += xs[j] * w0[j * HIDC + c];
    }
    float dn = dinv[n];
#pragma unroll
    for (int c = 0; c < HIDC; ++c) g1[(size_t)n * HIDC + c] = dn * acc[c];
}
__global__ void k_scatter1_f(const int* __restrict__ src, const int* __restrict__ dst,
                             const float* __restrict__ g1, float* __restrict__ acc1) {
    int i = blockIdx.x * blockDim.x + threadIdx.x;
    if (i >= EE * 4) return;
    int e = i >> 2, q = i & 3;
    float4 v = ((const float4*)g1)[src[e] * 4 + q];
    float* p = acc1 + (size_t)dst[e] * HIDC + q * 4;
    unsafeAtomicAdd(p + 0, v.x); unsafeAtomicAdd(p + 1, v.y);
    unsafeAtomicAdd(p + 2, v.z); unsafeAtomicAdd(p + 3, v.w);
}
__global__ void k_l2_f(const float* __restrict__ g1, const float* __restrict__ acc1,
                       const float* __restrict__ dinv, const float* __restrict__ b1,
                       const float* __restrict__ W2, float* __restrict__ g2) {
    int n = blockIdx.x * blockDim.x + threadIdx.x;
    if (n >= NN) return;
    float dn = dinv[n];
    float h[HIDC];
#pragma unroll
    for (int c = 0; c < HIDC; ++c)
        h[c] = fmaxf(dn * (acc1[(size_t)n * HIDC + c] + g1[(size_t)n * HIDC + c]) + b1[c], 0.f);
    float o0 = 0.f, o1 = 0.f;
#pragma unroll
    for (int c = 0; c < HIDC; ++c) { o0 += h[c] * W2[c * 2]; o1 += h[c] * W2[c * 2 + 1]; }
    g2[(size_t)n * 2] = dn * o0; g2[(size_t)n * 2 + 1] = dn * o1;
}
__global__ void k_scatter2_f(const int* __restrict__ src, const int* __restrict__ dst,
                             const float* __restrict__ g2, float* __restrict__ acc2) {
    int e = blockIdx.x * blockDim.x + threadIdx.x;
    if (e >= EE) return;
    float2 v = ((const float2*)g2)[src[e]];
    unsafeAtomicAdd(&acc2[(size_t)dst[e] * 2], v.x);
    unsafeAtomicAdd(&acc2[(size_t)dst[e] * 2 + 1], v.y);
}
__global__ void k_final_f(const float* __restrict__ g2, const float* __restrict__ acc2,
                          const float* __restrict__ dinv, const float* __restrict__ b2,
                          float* __restrict__ out) {
    int n = blockIdx.x * blockDim.x + threadIdx.x;
    if (n >= NN) return;
    float dn = dinv[n];
    float2 a = ((const float2*)acc2)[n];
    float2 g = ((const float2*)g2)[n];
    float2 o;
    o.x = dn * (a.x + g.x) + b2[0];
    o.y = dn * (a.y + g.y) + b2[1];
    ((float2*)out)[n] = o;
}

// ======================= launch =============================================

extern "C" void kernel_launch(void* const* d_in, const int* in_sizes, int n_in,
                              void* d_out, int out_size, void* d_ws, size_t ws_size,
                              hipStream_t stream) {
    const float* x  = (const float*)d_in[0];
    const int*   ei = (const int*)d_in[1];     // [2, E] flat: src then dst
    const float* W1 = (const float*)d_in[2];
    const float* b1 = (const float*)d_in[3];
    const float* W2 = (const float*)d_in[4];
    const float* b2 = (const float*)d_in[5];
    float* out = (float*)d_out;

    const int* src = ei;
    const int* dst = ei + EE;
    const int B = 256;

    // CSR-path workspace (4 B elements), total ~38.4 MB:
    //   gcur        [0, NT)
    //   brec/csr    [NT, NT + NT*SCAP)   fixed-capacity tile segments
    //   nstart      [.., + N+1)
    //   ndeg        [.., + N)
    //   g1 (fp16)   [.., + 8N)   16 halves/row
    //   g2 (fp32)   [.., + 2N)
    size_t need = ((size_t)NT + (size_t)NT * SCAP + (size_t)(NN + 1) + (size_t)NN +
                   (size_t)8 * NN + (size_t)2 * NN) * 4;
    if (ws_size >= need) {
        int* ws          = (int*)d_ws;
        int* gcur        = ws;
        int* brec        = ws + NT;                   // becomes node-sorted CSR
        int* nstart      = brec + (size_t)NT * SCAP;
        int* ndeg        = nstart + NN + 1;
        __half2* g1      = (__half2*)(ndeg + NN);
        float* g2        = (float*)((int*)(ndeg + NN) + (size_t)8 * NN);

        k_init  <<<1, 1024, 0, stream>>>(gcur);
        k_place <<<NBE, 256, 0, stream>>>(src, dst, gcur, brec);
        k_sortt <<<NT, 256, 0, stream>>>(brec, gcur, nstart, ndeg);
        k_xw    <<<(NN + 255) / 256, 256, 0, stream>>>(x, W1, ndeg, g1);
        k_agg1n <<<(NN * 8 + 255) / 256, 256, 0, stream>>>(brec, nstart, ndeg, g1, b1, W2, g2);
        k_agg2n <<<(NN * 8 + 255) / 256, 256, 0, stream>>>(brec, nstart, ndeg, g2, b2, out);
        return;
    }

    // -------- fallback: atomic-scatter path (needs 38N floats ~ 30.4 MB) ----
    char* wsb = (char*)d_ws;
    int*   deg  = (int*)wsb;
    float* acc1 = (float*)(wsb + (size_t)NN * 4);
    float* acc2 = (float*)(wsb + (size_t)17 * NN * 4);
    float* dinv = (float*)(wsb + (size_t)19 * NN * 4);
    float* g1   = (float*)(wsb + (size_t)20 * NN * 4);
    float* g2   = (float*)(wsb + (size_t)36 * NN * 4);

    hipMemsetAsync(d_ws, 0, (size_t)19 * NN * 4, stream);

    int gN = (NN + B - 1) / B, gE = (EE + B - 1) / B, gE4 = (EE * 4 + B - 1) / B;
    k_deg_f     <<<gE, B, 0, stream>>>(dst, deg);
    k_dinv_f    <<<gN, B, 0, stream>>>(deg, dinv);
    k_xw_f      <<<gN, B, 0, stream>>>(x, W1, dinv, g1);
    k_scatter1_f<<<gE4, B, 0, stream>>>(src, dst, g1, acc1);
    k_l2_f      <<<gN, B, 0, stream>>>(g1, acc1, dinv, b1, W2, g2);
    k_scatter2_f<<<gE, B, 0, stream>>>(src, dst, g2, acc2);
    k_final_f   <<<gN, B, 0, stream>>>(g2, acc2, dinv, b2, out);
}